// Round 12
// baseline (49.393 us; speedup 1.0000x reference)
//
#include <hip/hip_runtime.h>

#define NFILT 80
#define NBINS 257            // 512/2+1
#define NPTS  82             // binpoints
#define ROWS  16             // rows per tile
#define TFLOAT (ROWS * NBINS)   // 4112 floats = 16448 B
#define NCH   4              // filter chunks per wave (lane>>4)
#define FPC   20             // filters per chunk
#define OP2   81             // out-staging row stride (conflict-free)

// Single-wave blocks: no barriers anywhere. 9 blocks/CU (LDS-capped);
// block turnover provides stage/compute overlap across 9 independent
// streams. Lane (c,r) = (lane>>4, lane&15): chunk c sweeps segments
// 20c..20c+20 of row r with streaming moments (S0, S1) -- per-bin weights
// never materialize, so the inner loop is 1 LDS read + 2 FMA per bin.
__global__ __launch_bounds__(64, 2) void filter_kernel(
        const float* __restrict__ x, const float* __restrict__ bp,
        float* __restrict__ out) {
    __shared__ __align__(16) float sx[TFLOAT];  // x-tile; head reused for out
    __shared__ float sb[NPTS];                  // sorted binpoints
    __shared__ float sD[NPTS];                  // invD per segment
    __shared__ int   sli[NPTS];                 // floor(b[s]) + sentinel
    // total ~17.4 KB -> 9 blocks/CU

    const int lane = threadIdx.x;
    const int tile = blockIdx.x;
    const float* gsrc = x + (size_t)tile * TFLOAT;

    // ---- bp loads FIRST (oldest vmcnt ops -> readable without draining DMA)
    const int i0 = lane, i1 = lane + 64;
    float v0 = 0.f, v1 = 0.f;
    if (i0 < NPTS) v0 = bp[i0];
    if (i1 < NPTS) v1 = bp[i1];

    // ---- async DMA of the 16-row tile: 1028 chunks = 16/lane + 4 extra ----
#pragma unroll
    for (int j = 0; j < 16; ++j) {
        const int ci = lane + j * 64;
        __builtin_amdgcn_global_load_lds(
            (const __attribute__((address_space(1))) void*)(gsrc + ci * 4),
            (__attribute__((address_space(3))) void*)(sx + ci * 4), 16, 0, 0);
    }
    if (lane < 4) {
        const int ci = 1024 + lane;
        __builtin_amdgcn_global_load_lds(
            (const __attribute__((address_space(1))) void*)(gsrc + ci * 4),
            (__attribute__((address_space(3))) void*)(sx + ci * 4), 16, 0, 0);
    }

    // ---- table prep under the DMA (needs only the bp loads) ----
    if (i0 < NPTS) { sb[i0] = v0; sli[i0] = (int)floorf(v0); }
    if (i1 < NPTS) { sb[i1] = v1; sli[i1] = (int)floorf(v1); }
    asm volatile("s_waitcnt lgkmcnt(0)" ::: "memory");

    bool bad = false;
    if (i0 < NPTS - 1) bad = sb[i0] > sb[i0 + 1];
    if (i1 < NPTS - 1) bad = bad || (sb[i1] > sb[i1 + 1]);
    if (__any(bad)) {                   // rare: input unsorted
        if (lane == 0) {
            for (int i = 1; i < NPTS; ++i) {
                float v = sb[i]; int j = i - 1;
                while (j >= 0 && sb[j] > v) { sb[j + 1] = sb[j]; --j; }
                sb[j + 1] = v;
            }
            for (int i = 0; i < NPTS; ++i) sli[i] = (int)floorf(sb[i]);
        }
        asm volatile("s_waitcnt lgkmcnt(0)" ::: "memory");
    }
    {   // invD per segment s (d integer-valued: D==0 -> 1 per reference)
        float bs = sb[i0], bs1 = sb[i0 + 1];
        float d = bs1 - bs, D = d * d;
        sD[i0] = (D == 0.f) ? 1.f : 1.f / D;
    }
    if (i1 < NPTS - 1) {
        float bs = sb[i1], bs1 = sb[i1 + 1];
        float d = bs1 - bs, D = d * d;
        sD[i1] = (D == 0.f) ? 1.f : 1.f / D;
    }
    if (lane == 0) sli[NPTS - 1] = sli[NPTS - 2];  // sentinel: seg 80 empty
    asm volatile("s_waitcnt lgkmcnt(0)" ::: "memory");
    asm volatile("s_waitcnt vmcnt(0)" ::: "memory");   // tile landed

    // ---- compute: 21 unrolled segments, streaming moments ----
    const int c = lane >> 4;            // chunk 0..3
    const int r = lane & 15;            // row within tile
    const int rbase = r * NBINS;
    const int fbase = FPC * c;          // 0,20,40,60

    float res[FPC];
#pragma unroll
    for (int e = 0; e < FPC; ++e) res[e] = 0.f;

    int k = sli[fbase];                 // per-lane start bin
#pragma unroll
    for (int e = 0; e <= FPC; ++e) {    // static unroll -> static res indices
        const int s = fbase + e;
        const int   k1   = sli[s + 1];  // per-lane bounds (short divergent loop)
        const float bs   = sb[s];
        const float bs1  = sb[s + 1];
        const float invD = sD[s];
        const float k0f  = (float)k;
        float S0 = 0.f, S1 = 0.f, kk = 0.f;
        if (k < k1) {                   // load-ahead software pipeline
            float xv = sx[rbase + k];
            while (k + 1 < k1) {
                float xn = sx[rbase + k + 1];
                S0 += xv; S1 = fmaf(kk, xv, S1);
                kk += 1.f; ++k; xv = xn;
            }
            S0 += xv; S1 = fmaf(kk, xv, S1); ++k;
        }
        // rise of filter s, fall of filter s-1 (k0-offset avoids cancellation)
        if (e <= FPC - 1) res[e]     = fmaf(invD, S1 - (bs  - k0f) * S0, res[e]);
        if (e >= 1)       res[e - 1] = fmaf(invD, (bs1 - k0f) * S0 - S1, res[e - 1]);
    }
    if (c == 0)       res[0] = sx[rbase];     // filtered[:,:,0] = x[:,:,0]
    if (c == NCH - 1) res[FPC - 1] = 0.f;     // fbank row 79 is zeros

    // ---- transpose through the (now dead) head of sx, then store ----
    asm volatile("s_waitcnt lgkmcnt(0)" ::: "memory");
#pragma unroll
    for (int e = 0; e < FPC; ++e) sx[r * OP2 + fbase + e] = res[e];
    asm volatile("s_waitcnt lgkmcnt(0)" ::: "memory");

    float4* ob4 = (float4*)(out + (size_t)tile * (ROWS * NFILT));
#pragma unroll
    for (int j = 0; j < 5; ++j) {       // 320 float4s by 64 lanes
        const int i4 = lane + j * 64;
        const int ib = i4 * 4;
        const int rr = ib / NFILT;
        const int ff = ib - rr * NFILT; // 80%4==0 -> float4 within one row
        float4 v;
        v.x = sx[rr * OP2 + ff];
        v.y = sx[rr * OP2 + ff + 1];
        v.z = sx[rr * OP2 + ff + 2];
        v.w = sx[rr * OP2 + ff + 3];
        ob4[i4] = v;                    // coalesced 1KB per instr
    }
}

extern "C" void kernel_launch(void* const* d_in, const int* in_sizes, int n_in,
                              void* d_out, int out_size, void* d_ws, size_t ws_size,
                              hipStream_t stream) {
    const float* x  = (const float*)d_in[0];
    const float* bp = (const float*)d_in[1];
    float* out = (float*)d_out;

    const int nrows = in_sizes[0] / NBINS;   // 131072
    const int tiles = nrows / ROWS;          // 8192 (exact)

    filter_kernel<<<tiles, 64, 0, stream>>>(x, bp, out);
}

// Round 13
// 36.029 us; speedup vs baseline: 1.3709x; 1.3709x over previous
//
#include <hip/hip_runtime.h>

#define NFILT 80
#define NBINS 257            // 512/2+1
#define NPTS  82             // binpoints
#define ROWS  32             // rows per tile
#define BLOCK 512            // 8 waves
#define GRID  1024           // 4 blocks per CU
#define OPAD  81             // out-staging row stride (conflict-free)
#define TFLOAT (ROWS * NBINS)            // 8224 floats = 32896 B
#define CHUNKS (TFLOAT / 4)              // 2056 = 512*4 + 8
#define FPG   5              // filters per 32-lane group (16 groups x 5 = 80)
#define SPT   ((ROWS * NFILT) / BLOCK)   // store elems per thread = 5

// Async DMA one tile (33KB) global->LDS. 4 instrs/thread; wave0 lanes 0-7
// issue 1 extra for chunks 2048..2055. Per-wave vmcnt ops: wave0=5, else 4.
__device__ __forceinline__ void stage(const float* __restrict__ x, int tg,
                                      float* ldst, int tid, int wv, int lane) {
    const float* gsrc = x + (size_t)tg * TFLOAT;
#pragma unroll
    for (int j = 0; j < 4; ++j) {
        int ci = tid + j * BLOCK;
        __builtin_amdgcn_global_load_lds(
            (const __attribute__((address_space(1))) void*)(gsrc + ci * 4),
            (__attribute__((address_space(3))) void*)(ldst + ci * 4), 16, 0, 0);
    }
    if (wv == 0 && lane < 8) {
        int ci = 2048 + lane;
        __builtin_amdgcn_global_load_lds(
            (const __attribute__((address_space(1))) void*)(gsrc + ci * 4),
            (__attribute__((address_space(3))) void*)(ldst + ci * 4), 16, 0, 0);
    }
}

// 4 independent 8-wave streams per CU (100% occupancy). Per block: 32-row
// tiles, single-buffered; R8 phase structure (compute -> transpose through
// dead tile head -> coalesced stores; DMA issued before stores, vmcnt(5)
// retires the DMA and keeps stores in flight across the tile boundary).
// Lane=(g,r): group G=2*wv+g owns filters [5G,5G+5), sweeps segments
// 5G..5G+5 for row r. Only 2-way bound divergence per wave; LDS x-reads
// bank = (r+k)%32 per group -> <=2-way aliasing (free).
__global__ __launch_bounds__(BLOCK, 8) void filter_kernel(
        const float* __restrict__ x, const float* __restrict__ bp,
        float* __restrict__ out, int tiles) {
    __shared__ __align__(16) float sx[TFLOAT];      // 32896 B (head -> sout)
    __shared__ __align__(8)  float sw[2 * NBINS];   // 2056 B
    __shared__ float sb[NPTS];                      // 328 B
    __shared__ int   sli[NPTS];                     // 328 B floor(b[s])+sentinel
    __shared__ int   sflag;
    // ~35.6 KB -> 4 blocks/CU

    const int tid  = threadIdx.x;
    const int lane = tid & 63;
    const int wv   = __builtin_amdgcn_readfirstlane(tid >> 6);
    const int g    = lane >> 5;            // group within wave
    const int r    = lane & 31;            // row within tile
    const int G    = 2 * wv + g;           // filter-group 0..15
    const int fa   = FPG * G;              // filters [fa, fa+5)

    const int bid  = blockIdx.x;
    const int base = tiles / GRID, rem = tiles % GRID;
    const int t0   = bid * base + min(bid, rem);
    const int cnt  = base + (bid < rem ? 1 : 0);
    if (cnt <= 0) return;

    // ---- prologue: T0 DMA first, table prep under its latency ----
    stage(x, t0, sx, tid, wv, lane);
    if (tid == 0) sflag = 0;
    if (tid < NPTS) sb[tid] = bp[tid];
    for (int i = tid; i < 2 * NBINS; i += BLOCK) sw[i] = 0.f;
    __syncthreads();
    if (tid < NPTS - 1 && sb[tid] > sb[tid + 1]) sflag = 1;
    __syncthreads();
    if (sflag) {                           // input unsorted (not expected)
        if (tid == 0) {
            for (int i = 1; i < NPTS; ++i) {
                float v = sb[i]; int j = i - 1;
                while (j >= 0 && sb[j] > v) { sb[j + 1] = sb[j]; --j; }
                sb[j + 1] = v;
            }
        }
        __syncthreads();
    }
    if (tid <= 80) sli[tid] = (int)floorf(sb[tid]);
    if (tid == 81) sli[81] = (int)floorf(sb[80]);   // sentinel: seg 80 empty
    __syncthreads();
    if (tid < 80) {                        // thread s fills its segment's bins
        int s  = tid;
        int k0 = sli[s], k1 = sli[s + 1];
        float bs = sb[s], bs1 = sb[s + 1];
        float d = bs1 - bs, D = d * d;
        float invD = (D == 0.f) ? 1.f : 1.f / D;
        for (int k = k0; k < k1; ++k) {
            sw[2 * k]     = (s <= 78) ? ((float)k - bs) * invD : 0.f;  // rise(s)
            sw[2 * k + 1] = (s >= 1)  ? (bs1 - (float)k) * invD : 0.f; // fall(s-1)
        }
    }
    asm volatile("s_waitcnt vmcnt(0)" ::: "memory");   // T0 landed
    __syncthreads();                                   // tables visible

    const float2* swp = (const float2*)sw;

    for (int tl = 0; tl < cnt; ++tl) {
        // head invariant: sx holds tile t0+tl, landed for all waves
        const float* xr = &sx[r * NBINS];

        // ---- compute: 6 segments (group-uniform bounds), 5 reg outputs ----
        float res[FPG];
        float xv0 = xr[0];
        int k = sli[fa];                   // group-uniform (per-lane value)
        float r_prev = 0.f;
#pragma unroll
        for (int e = 0; e <= FPG; ++e) {   // static unroll -> static indices
            const int s  = fa + e;
            const int k1 = sli[s + 1];
            float racc = 0.f, facc = 0.f;
            if (k < k1) {                  // load-ahead software pipeline
                float  xv = xr[k];
                float2 w2 = swp[k];
                for (; k + 1 < k1; ++k) {
                    float  xn = xr[k + 1];
                    float2 wn = swp[k + 1];
                    racc = fmaf(xv, w2.x, racc);
                    facc = fmaf(xv, w2.y, facc);
                    xv = xn; w2 = wn;
                }
                racc = fmaf(xv, w2.x, racc);
                facc = fmaf(xv, w2.y, facc);
                ++k;
            }
            if (e > 0) res[e - 1] = r_prev + facc;  // filter fa+e-1
            r_prev = racc;
        }
        if (G == 0)  res[0] = xv0;         // filtered[:,:,0] = x[:,:,0]
        if (G == 15) res[FPG - 1] = 0.f;   // fbank row 79 is zeros

        asm volatile("s_waitcnt lgkmcnt(0)" ::: "memory");
        __builtin_amdgcn_s_barrier();      // B1: x-reads done -> sx head dead
        __builtin_amdgcn_sched_barrier(0);

        // ---- transpose: res -> head of sx as [ROWS][OPAD] ----
        {
            float* so = sx + r * OPAD;
#pragma unroll
            for (int e = 0; e < FPG; ++e) so[fa + e] = res[e];
        }
        asm volatile("s_waitcnt lgkmcnt(0)" ::: "memory");
        __builtin_amdgcn_s_barrier();      // B2: staging visible
        __builtin_amdgcn_sched_barrier(0);

        // ---- pull coalesced store data into VGPRs ----
        float vout[SPT];
#pragma unroll
        for (int j = 0; j < SPT; ++j) {
            int i = tid + j * BLOCK;
            int rr = i / NFILT;
            vout[j] = sx[rr * OPAD + (i - rr * NFILT)];
        }
        float* ob = out + (size_t)(t0 + tl) * (ROWS * NFILT);

        if (tl == cnt - 1) {               // last tile: store and exit
#pragma unroll
            for (int j = 0; j < SPT; ++j) ob[tid + j * BLOCK] = vout[j];
            break;
        }

        asm volatile("s_waitcnt lgkmcnt(0)" ::: "memory");
        __builtin_amdgcn_s_barrier();      // B3: vout reads done -> sx free
        __builtin_amdgcn_sched_barrier(0);

        // ---- DMA(tl+1) FIRST (oldest), then stores (newest) ----
        stage(x, t0 + tl + 1, sx, tid, wv, lane);
        __builtin_amdgcn_sched_barrier(0);
#pragma unroll
        for (int j = 0; j < SPT; ++j) ob[tid + j * BLOCK] = vout[j];
        __builtin_amdgcn_sched_barrier(0);
        // outstanding: old stores (retired first) + DMA 4|5 + stores 5.
        // vmcnt(5) retires DMA fully, keeps the 5 new stores in flight:
        asm volatile("s_waitcnt vmcnt(5)" ::: "memory");
        __builtin_amdgcn_sched_barrier(0);
        __builtin_amdgcn_s_barrier();      // B4: tile tl+1 landed for ALL waves
        __builtin_amdgcn_sched_barrier(0);
    }
}

extern "C" void kernel_launch(void* const* d_in, const int* in_sizes, int n_in,
                              void* d_out, int out_size, void* d_ws, size_t ws_size,
                              hipStream_t stream) {
    const float* x  = (const float*)d_in[0];
    const float* bp = (const float*)d_in[1];
    float* out = (float*)d_out;

    const int nrows = in_sizes[0] / NBINS;   // 131072
    const int tiles = nrows / ROWS;          // 4096

    filter_kernel<<<GRID, BLOCK, 0, stream>>>(x, bp, out, tiles);
}